// Round 1
// baseline (11036.359 us; speedup 1.0000x reference)
//
#include <hip/hip_runtime.h>
#include <hip/hip_bf16.h>
#include <math.h>
#include <stddef.h>

// Problem constants
#define BATCH  4
#define SEQ    1024
#define DIM    1024
#define NCHUNK 128
#define NHEAD  16
#define HDIM   64
#define NLAYER 4
#define FFDIM  4096
#define MROWS  (BATCH*SEQ)   // 4096
#define EPSV   1e-5f

// ---------------------------------------------------------------------------
// 1. Ragged gather: x[b,l,:] = x_processed[b, idx(b,l), :] + x_residual[b,l,:]
//    idx = searchsorted(boundaries[b], l, 'right') - 1, clipped.
// ---------------------------------------------------------------------------
__global__ __launch_bounds__(256) void gather_kernel(
    const float* __restrict__ xp, const int* __restrict__ bnd,
    const float* __restrict__ xres, float* __restrict__ x)
{
    int blk = blockIdx.x;                 // b*SEQ + l
    int b = blk >> 10, l = blk & (SEQ - 1);
    __shared__ int sidx;
    if (threadIdx.x == 0) {
        const int* bb = bnd + b * NCHUNK;
        int lo = 0, hi = NCHUNK;
        while (lo < hi) { int mid = (lo + hi) >> 1; if (bb[mid] <= l) lo = mid + 1; else hi = mid; }
        int idx = lo - 1;
        idx = idx < 0 ? 0 : (idx > NCHUNK - 1 ? NCHUNK - 1 : idx);
        sidx = idx;
    }
    __syncthreads();
    int idx = sidx;
    int t = threadIdx.x;
    float4 a = *(const float4*)&xp[((size_t)b * NCHUNK + idx) * DIM + t * 4];
    float4 r = *(const float4*)&xres[(size_t)blk * DIM + t * 4];
    float4 o; o.x = a.x + r.x; o.y = a.y + r.y; o.z = a.z + r.z; o.w = a.w + r.w;
    *(float4*)&x[(size_t)blk * DIM + t * 4] = o;
}

// ---------------------------------------------------------------------------
// 2. RMSNorm: one block per row of 1024
// ---------------------------------------------------------------------------
__global__ __launch_bounds__(256) void rmsnorm_kernel(
    const float* __restrict__ x, const float* __restrict__ w, float* __restrict__ out)
{
    int row = blockIdx.x;
    int t = threadIdx.x;
    const float4 xv = *(const float4*)&x[(size_t)row * DIM + t * 4];
    float ss = xv.x * xv.x + xv.y * xv.y + xv.z * xv.z + xv.w * xv.w;
    #pragma unroll
    for (int m = 1; m < 64; m <<= 1) ss += __shfl_xor(ss, m);
    __shared__ float ws_[4];
    if ((t & 63) == 0) ws_[t >> 6] = ss;
    __syncthreads();
    float tot = ws_[0] + ws_[1] + ws_[2] + ws_[3];
    float rs = rsqrtf(tot * (1.0f / DIM) + EPSV);
    const float4 wv = *(const float4*)&w[t * 4];
    float4 o;
    o.x = xv.x * rs * wv.x; o.y = xv.y * rs * wv.y;
    o.z = xv.z * rs * wv.z; o.w = xv.w * rs * wv.w;
    *(float4*)&out[(size_t)row * DIM + t * 4] = o;
}

// ---------------------------------------------------------------------------
// 3. fp32 tiled GEMM: C[M,N] (+)= A[M,Kd] @ B[Kd,N]
//    128x64 tile, 256 threads, 8x4 per thread, BK=16.
//    MODE 0: C = AB   MODE 1: C += AB   MODE 2: C = silu(AB) * C
// ---------------------------------------------------------------------------
#define GBM 128
#define GBN 64
#define GBK 16

template<int MODE>
__global__ __launch_bounds__(256) void gemm_f32(
    const float* __restrict__ A, const float* __restrict__ Bm,
    float* __restrict__ C, int N, int Kd)
{
    __shared__ float As[GBK][GBM + 4];
    __shared__ float Bs[GBK][GBN];
    int t = threadIdx.x;
    int tx = t & 15, ty = t >> 4;
    int bn = blockIdx.x * GBN;
    int bm = blockIdx.y * GBM;
    float acc[8][4] = {};
    for (int k0 = 0; k0 < Kd; k0 += GBK) {
        #pragma unroll
        for (int i = 0; i < 2; ++i) {
            int idx = t + i * 256;
            int row = idx >> 2, c4 = (idx & 3) * 4;
            float4 av = *(const float4*)&A[(size_t)(bm + row) * Kd + k0 + c4];
            As[c4 + 0][row] = av.x; As[c4 + 1][row] = av.y;
            As[c4 + 2][row] = av.z; As[c4 + 3][row] = av.w;
        }
        {
            int kk = t >> 4, c4 = (t & 15) * 4;
            *(float4*)&Bs[kk][c4] = *(const float4*)&Bm[(size_t)(k0 + kk) * N + bn + c4];
        }
        __syncthreads();
        #pragma unroll
        for (int kk = 0; kk < GBK; ++kk) {
            float a[8], bv[4];
            #pragma unroll
            for (int i = 0; i < 8; ++i) a[i] = As[kk][ty * 8 + i];
            #pragma unroll
            for (int j = 0; j < 4; ++j) bv[j] = Bs[kk][tx * 4 + j];
            #pragma unroll
            for (int i = 0; i < 8; ++i)
                #pragma unroll
                for (int j = 0; j < 4; ++j)
                    acc[i][j] = fmaf(a[i], bv[j], acc[i][j]);
        }
        __syncthreads();
    }
    #pragma unroll
    for (int i = 0; i < 8; ++i) {
        float* cp = &C[(size_t)(bm + ty * 8 + i) * N + bn + tx * 4];
        float4 r; r.x = acc[i][0]; r.y = acc[i][1]; r.z = acc[i][2]; r.w = acc[i][3];
        if (MODE == 1) {
            float4 p = *(const float4*)cp;
            r.x += p.x; r.y += p.y; r.z += p.z; r.w += p.w;
        } else if (MODE == 2) {
            float4 p = *(const float4*)cp;
            r.x = (r.x / (1.f + expf(-r.x))) * p.x;
            r.y = (r.y / (1.f + expf(-r.y))) * p.y;
            r.z = (r.z / (1.f + expf(-r.z))) * p.z;
            r.w = (r.w / (1.f + expf(-r.w))) * p.w;
        }
        *(float4*)cp = r;
    }
}

// ---------------------------------------------------------------------------
// 4. RoPE applied in-place to q and k, layout [B, L, H, HD]
//    out[d]    = x[d]*cos[d]    - x[d+32]*sin[d]
//    out[d+32] = x[d+32]*cos[d+32] + x[d]*sin[d+32]
// ---------------------------------------------------------------------------
__global__ __launch_bounds__(256) void rope_kernel(
    float* __restrict__ q, float* __restrict__ k,
    const float* __restrict__ cosb, const float* __restrict__ sinb)
{
    int gid = blockIdx.x * 256 + threadIdx.x;  // B*L*H*32
    int dp = gid & 31;
    int h  = (gid >> 5) & (NHEAD - 1);
    int l  = (gid >> 9) & (SEQ - 1);
    int b  = gid >> 19;
    size_t base = (((size_t)b * SEQ + l) * NHEAD + h) * HDIM;
    float c1 = cosb[l * HDIM + dp],      s1 = sinb[l * HDIM + dp];
    float c2 = cosb[l * HDIM + dp + 32], s2 = sinb[l * HDIM + dp + 32];
    float q1 = q[base + dp], q2 = q[base + dp + 32];
    q[base + dp]      = q1 * c1 - q2 * s1;
    q[base + dp + 32] = q2 * c2 + q1 * s2;
    float k1 = k[base + dp], k2 = k[base + dp + 32];
    k[base + dp]      = k1 * c1 - k2 * s1;
    k[base + dp + 32] = k2 * c2 + k1 * s2;
}

// ---------------------------------------------------------------------------
// 5. Causal flash attention, fp32. One block = (b, h, 32-row q-tile).
//    256 threads: thread t owns row r=t>>3, dims dbase=(t&7)*8 .. +7.
// ---------------------------------------------------------------------------
__global__ __launch_bounds__(256) void attn_kernel(
    const float* __restrict__ q, const float* __restrict__ k,
    const float* __restrict__ v, float* __restrict__ o)
{
    int blk = blockIdx.x;              // ((b*H + h)*32 + qt)
    int qt = blk & 31;
    int h  = (blk >> 5) & (NHEAD - 1);
    int b  = blk >> 9;
    int q0 = qt * 32;

    __shared__ float Qs[32][65];
    __shared__ float Ks[64][65];
    __shared__ float Vs[64][65];
    __shared__ float Ps[32][65];

    int t = threadIdx.x;
    int r = t >> 3;                // 0..31 (q row within tile)
    int c0 = (t & 7) * 8;          // column / dim base
    const float scale = 0.125f;    // 1/sqrt(64)

    // Load Q tile
    #pragma unroll
    for (int i = 0; i < 2; ++i) {
        int idx = t + i * 256;
        int row = idx >> 4, c4 = (idx & 15) * 4;
        float4 qv = *(const float4*)&q[(((size_t)b * SEQ + q0 + row) * NHEAD + h) * HDIM + c4];
        Qs[row][c4 + 0] = qv.x; Qs[row][c4 + 1] = qv.y;
        Qs[row][c4 + 2] = qv.z; Qs[row][c4 + 3] = qv.w;
    }
    __syncthreads();

    float acc[8] = {};
    float m = -1e30f, lsum = 0.f;

    int kend = q0 + 32;
    int nkt = (kend + 63) >> 6;
    for (int kt = 0; kt < nkt; ++kt) {
        int k0 = kt * 64;
        // Load K, V tiles (64x64 each)
        #pragma unroll
        for (int i = 0; i < 4; ++i) {
            int idx = t + i * 256;
            int row = idx >> 4, c4 = (idx & 15) * 4;
            size_t g = (((size_t)b * SEQ + k0 + row) * NHEAD + h) * HDIM + c4;
            float4 kv = *(const float4*)&k[g];
            Ks[row][c4 + 0] = kv.x; Ks[row][c4 + 1] = kv.y;
            Ks[row][c4 + 2] = kv.z; Ks[row][c4 + 3] = kv.w;
            float4 vv = *(const float4*)&v[g];
            Vs[row][c4 + 0] = vv.x; Vs[row][c4 + 1] = vv.y;
            Vs[row][c4 + 2] = vv.z; Vs[row][c4 + 3] = vv.w;
        }
        __syncthreads();

        // S = scale * Q K^T for this thread's 8 columns
        float s[8] = {};
        #pragma unroll 8
        for (int d = 0; d < 64; ++d) {
            float qd = Qs[r][d];
            #pragma unroll
            for (int jj = 0; jj < 8; ++jj) s[jj] = fmaf(qd, Ks[c0 + jj][d], s[jj]);
        }
        float tm = -1e30f;
        #pragma unroll
        for (int jj = 0; jj < 8; ++jj) {
            bool valid = (k0 + c0 + jj) <= (q0 + r);
            s[jj] = valid ? s[jj] * scale : -1e30f;
            tm = fmaxf(tm, s[jj]);
        }
        tm = fmaxf(tm, __shfl_xor(tm, 1));
        tm = fmaxf(tm, __shfl_xor(tm, 2));
        tm = fmaxf(tm, __shfl_xor(tm, 4));
        float mnew = fmaxf(m, tm);
        float sc = expf(m - mnew);
        float psum = 0.f;
        #pragma unroll
        for (int jj = 0; jj < 8; ++jj) {
            float p = (s[jj] > -1e29f) ? expf(s[jj] - mnew) : 0.f;
            Ps[r][c0 + jj] = p;
            psum += p;
        }
        psum += __shfl_xor(psum, 1);
        psum += __shfl_xor(psum, 2);
        psum += __shfl_xor(psum, 4);
        lsum = lsum * sc + psum;
        m = mnew;
        #pragma unroll
        for (int i = 0; i < 8; ++i) acc[i] *= sc;
        __syncthreads();

        // O += P V
        for (int j = 0; j < 64; ++j) {
            float p = Ps[r][j];
            #pragma unroll
            for (int i = 0; i < 8; ++i) acc[i] = fmaf(p, Vs[j][c0 + i], acc[i]);
        }
        __syncthreads();
    }

    float inv = 1.0f / lsum;
    size_t ob = (((size_t)b * SEQ + q0 + r) * NHEAD + h) * HDIM + c0;
    #pragma unroll
    for (int i = 0; i < 8; ++i) o[ob + i] = acc[i] * inv;
}

// ---------------------------------------------------------------------------
// Launch
// ---------------------------------------------------------------------------
extern "C" void kernel_launch(void* const* d_in, const int* in_sizes, int n_in,
                              void* d_out, int out_size, void* d_ws, size_t ws_size,
                              hipStream_t stream)
{
    const float* xp   = (const float*)d_in[0];
    const int*   bnd  = (const int*)d_in[1];
    // d_in[2] = counts (unused by reference math)
    const float* xres = (const float*)d_in[3];
    const float* cosb = (const float*)d_in[4];
    const float* sinb = (const float*)d_in[5];
    // d_in[6] = seq_len scalar (compile-time constant here)
    const float* wq = (const float*)d_in[7];
    const float* wk = (const float*)d_in[8];
    const float* wv = (const float*)d_in[9];
    const float* wo = (const float*)d_in[10];
    const float* w1 = (const float*)d_in[11];
    const float* w2 = (const float*)d_in[12];
    const float* w3 = (const float*)d_in[13];
    const float* anw = (const float*)d_in[14];
    const float* fnw = (const float*)d_in[15];
    const float* nw  = (const float*)d_in[16];

    float* ws = (float*)d_ws;
    const size_t SZ = (size_t)MROWS * DIM;   // 4M floats = 16MB
    float* x  = ws;             // 16MB
    float* h  = ws + SZ;        // 16MB
    float* qb = ws + 2 * SZ;    // 16MB
    float* kb = ws + 3 * SZ;    // 16MB
    float* vb = ws + 4 * SZ;    // 16MB
    float* ob = ws + 5 * SZ;    // 16MB
    float* g  = ws + 2 * SZ;    // 64MB FFN buffer, aliases q|k|v|o (dead in FFN phase)

    dim3 blk(256);
    dim3 gemmD(DIM / GBN, MROWS / GBM);    // N=1024
    dim3 gemmF(FFDIM / GBN, MROWS / GBM);  // N=4096

    gather_kernel<<<MROWS, blk, 0, stream>>>(xp, bnd, xres, x);

    for (int l = 0; l < NLAYER; ++l) {
        const float* wql = wq + (size_t)l * DIM * DIM;
        const float* wkl = wk + (size_t)l * DIM * DIM;
        const float* wvl = wv + (size_t)l * DIM * DIM;
        const float* wol = wo + (size_t)l * DIM * DIM;
        const float* w1l = w1 + (size_t)l * DIM * FFDIM;
        const float* w2l = w2 + (size_t)l * FFDIM * DIM;
        const float* w3l = w3 + (size_t)l * DIM * FFDIM;

        // attention block
        rmsnorm_kernel<<<MROWS, blk, 0, stream>>>(x, anw + (size_t)l * DIM, h);
        gemm_f32<0><<<gemmD, blk, 0, stream>>>(h, wql, qb, DIM, DIM);
        gemm_f32<0><<<gemmD, blk, 0, stream>>>(h, wkl, kb, DIM, DIM);
        gemm_f32<0><<<gemmD, blk, 0, stream>>>(h, wvl, vb, DIM, DIM);
        rope_kernel<<<(BATCH * SEQ * NHEAD * 32) / 256, blk, 0, stream>>>(qb, kb, cosb, sinb);
        attn_kernel<<<BATCH * NHEAD * (SEQ / 32), blk, 0, stream>>>(qb, kb, vb, ob);
        gemm_f32<1><<<gemmD, blk, 0, stream>>>(ob, wol, x, DIM, DIM);   // x += o @ wo

        // FFN block
        rmsnorm_kernel<<<MROWS, blk, 0, stream>>>(x, fnw + (size_t)l * DIM, h);
        gemm_f32<0><<<gemmF, blk, 0, stream>>>(h, w3l, g, FFDIM, DIM);  // g = h @ w3
        gemm_f32<2><<<gemmF, blk, 0, stream>>>(h, w1l, g, FFDIM, DIM);  // g = silu(h@w1) * g
        gemm_f32<1><<<gemmD, blk, 0, stream>>>(g, w2l, x, DIM, FFDIM);  // x += g @ w2
    }

    rmsnorm_kernel<<<MROWS, blk, 0, stream>>>(x, nw, (float*)d_out);
}

// Round 2
// 5360.418 us; speedup vs baseline: 2.0589x; 2.0589x over previous
//
#include <hip/hip_runtime.h>
#include <hip/hip_bf16.h>
#include <math.h>
#include <stddef.h>
#include <stdint.h>

#define BATCH  4
#define SEQ    1024
#define DIM    1024
#define NCHUNK 128
#define NHEAD  16
#define HDIM   64
#define NLAYER 4
#define FFDIM  4096
#define MROWS  (BATCH*SEQ)   // 4096
#define EPSV   1e-5f

typedef __bf16 bf16x8 __attribute__((ext_vector_type(8)));
typedef float  f32x4  __attribute__((ext_vector_type(4)));

__device__ __forceinline__ float bf2f(unsigned short u) {
    unsigned int x = ((unsigned int)u) << 16;
    return __builtin_bit_cast(float, x);
}
__device__ __forceinline__ unsigned short f2bf(float f) {
    unsigned int x = __builtin_bit_cast(unsigned int, f);
    x += 0x7fff + ((x >> 16) & 1);          // RNE
    return (unsigned short)(x >> 16);
}

// async global->LDS, 16B per lane (linear LDS dest in lane order!)
__device__ __forceinline__ void gload16(const void* g, void* l) {
    __builtin_amdgcn_global_load_lds((const __attribute__((address_space(1))) void*)g,
                                     (__attribute__((address_space(3))) void*)l, 16, 0, 0);
}

// ---------------------------------------------------------------------------
// 1. Ragged gather (fp32): x = gather(x_processed) + x_residual
// ---------------------------------------------------------------------------
__global__ __launch_bounds__(256) void gather_kernel(
    const float* __restrict__ xp, const int* __restrict__ bnd,
    const float* __restrict__ xres, float* __restrict__ x)
{
    int blk = blockIdx.x;
    int b = blk >> 10, l = blk & (SEQ - 1);
    __shared__ int sidx;
    if (threadIdx.x == 0) {
        const int* bb = bnd + b * NCHUNK;
        int lo = 0, hi = NCHUNK;
        while (lo < hi) { int mid = (lo + hi) >> 1; if (bb[mid] <= l) lo = mid + 1; else hi = mid; }
        int idx = lo - 1;
        sidx = idx < 0 ? 0 : (idx > NCHUNK - 1 ? NCHUNK - 1 : idx);
    }
    __syncthreads();
    int idx = sidx;
    int t = threadIdx.x;
    float4 a = *(const float4*)&xp[((size_t)b * NCHUNK + idx) * DIM + t * 4];
    float4 r = *(const float4*)&xres[(size_t)blk * DIM + t * 4];
    float4 o; o.x = a.x + r.x; o.y = a.y + r.y; o.z = a.z + r.z; o.w = a.w + r.w;
    *(float4*)&x[(size_t)blk * DIM + t * 4] = o;
}

// ---------------------------------------------------------------------------
// 2. RMSNorm (fp32 in). OUTBF=1 -> bf16 out, else fp32 out.
// ---------------------------------------------------------------------------
template<int OUTBF>
__global__ __launch_bounds__(256) void rmsnorm_kernel(
    const float* __restrict__ x, const float* __restrict__ w, void* __restrict__ out)
{
    int row = blockIdx.x;
    int t = threadIdx.x;
    const float4 xv = *(const float4*)&x[(size_t)row * DIM + t * 4];
    float ss = xv.x * xv.x + xv.y * xv.y + xv.z * xv.z + xv.w * xv.w;
    #pragma unroll
    for (int m = 1; m < 64; m <<= 1) ss += __shfl_xor(ss, m);
    __shared__ float ws_[4];
    if ((t & 63) == 0) ws_[t >> 6] = ss;
    __syncthreads();
    float tot = ws_[0] + ws_[1] + ws_[2] + ws_[3];
    float rs = rsqrtf(tot * (1.0f / DIM) + EPSV);
    const float4 wv = *(const float4*)&w[t * 4];
    float4 o;
    o.x = xv.x * rs * wv.x; o.y = xv.y * rs * wv.y;
    o.z = xv.z * rs * wv.z; o.w = xv.w * rs * wv.w;
    if (OUTBF) {
        ushort4 p;
        p.x = f2bf(o.x); p.y = f2bf(o.y); p.z = f2bf(o.z); p.w = f2bf(o.w);
        *(ushort4*)&((unsigned short*)out)[(size_t)row * DIM + t * 4] = p;
    } else {
        *(float4*)&((float*)out)[(size_t)row * DIM + t * 4] = o;
    }
}

// ---------------------------------------------------------------------------
// 3. Weight cast+transpose: W fp32 [Kd][N] -> WT bf16 [N][Kd]
// ---------------------------------------------------------------------------
__global__ __launch_bounds__(256) void castT_kernel(
    const float* __restrict__ W, unsigned short* __restrict__ WT, int Kd, int N)
{
    int n0 = blockIdx.x * 32, k0 = blockIdx.y * 32;
    __shared__ float tile[32][33];
    int t = threadIdx.x;
    int r = t >> 3, c4 = (t & 7) * 4;
    float4 v = *(const float4*)&W[(size_t)(k0 + r) * N + n0 + c4];
    tile[r][c4 + 0] = v.x; tile[r][c4 + 1] = v.y;
    tile[r][c4 + 2] = v.z; tile[r][c4 + 3] = v.w;
    __syncthreads();
    ushort4 p;
    p.x = f2bf(tile[c4 + 0][r]); p.y = f2bf(tile[c4 + 1][r]);
    p.z = f2bf(tile[c4 + 2][r]); p.w = f2bf(tile[c4 + 3][r]);
    *(ushort4*)&WT[(size_t)(n0 + r) * Kd + k0 + c4] = p;
}

// ---------------------------------------------------------------------------
// 4. bf16 MFMA GEMM (m97 structure): C[M,N] = A[M,Kd] @ WT[N,Kd]^T
//    128x128 tile, BK=32, 4 waves (2x2), 4x4 frags of 16x16x32 per wave.
//    MODE 0: C(bf16) = AB    MODE 1: C(fp32) += AB    MODE 2: C(bf16) = silu(AB)*C
// ---------------------------------------------------------------------------
template<int MODE>
__global__ __launch_bounds__(256) void gemm_bf16(
    const __bf16* __restrict__ A, const __bf16* __restrict__ WT,
    void* __restrict__ C, int N, int Kd)
{
    __shared__ __bf16 As[128 * 32];
    __shared__ __bf16 Bs[128 * 32];
    int t = threadIdx.x;
    int l = t & 63, w = t >> 6;
    int wr = w >> 1, wc = w & 1;
    int bm = blockIdx.y * 128, bn = blockIdx.x * 128;
    int l15 = l & 15, l4 = l >> 4;
    int kOff = l4 * 8;

    f32x4 acc[4][4];
    #pragma unroll
    for (int m = 0; m < 4; ++m)
        #pragma unroll
        for (int n = 0; n < 4; ++n)
            acc[m][n] = (f32x4){0.f, 0.f, 0.f, 0.f};

    for (int k0 = 0; k0 < Kd; k0 += 32) {
        #pragma unroll
        for (int i = 0; i < 2; ++i) {
            int idx = t + i * 256;
            gload16(A + (size_t)(bm + (idx >> 2)) * Kd + k0 + (idx & 3) * 8, &As[idx * 8]);
        }
        #pragma unroll
        for (int i = 0; i < 2; ++i) {
            int idx = t + i * 256;
            gload16(WT + (size_t)(bn + (idx >> 2)) * Kd + k0 + (idx & 3) * 8, &Bs[idx * 8]);
        }
        __syncthreads();
        bf16x8 af[4], bf[4];
        #pragma unroll
        for (int m = 0; m < 4; ++m)
            af[m] = *(const bf16x8*)&As[(wr * 64 + m * 16 + l15) * 32 + kOff];
        #pragma unroll
        for (int n = 0; n < 4; ++n)
            bf[n] = *(const bf16x8*)&Bs[(wc * 64 + n * 16 + l15) * 32 + kOff];
        #pragma unroll
        for (int m = 0; m < 4; ++m)
            #pragma unroll
            for (int n = 0; n < 4; ++n)
                acc[m][n] = __builtin_amdgcn_mfma_f32_16x16x32_bf16(af[m], bf[n], acc[m][n], 0, 0, 0);
        __syncthreads();
    }

    // epilogue: C/D layout col = l&15, row = (l>>4)*4 + reg
    int rBase = bm + wr * 64 + l4 * 4;
    int cBase = bn + wc * 64 + l15;
    #pragma unroll
    for (int m = 0; m < 4; ++m) {
        #pragma unroll
        for (int n = 0; n < 4; ++n) {
            int col = cBase + n * 16;
            #pragma unroll
            for (int r = 0; r < 4; ++r) {
                int row = rBase + m * 16 + r;
                float val = acc[m][n][r];
                if (MODE == 0) {
                    ((unsigned short*)C)[(size_t)row * N + col] = f2bf(val);
                } else if (MODE == 1) {
                    ((float*)C)[(size_t)row * N + col] += val;
                } else {
                    unsigned short* p = &((unsigned short*)C)[(size_t)row * N + col];
                    float gv = bf2f(*p);
                    float s = val / (1.f + expf(-val));
                    *p = f2bf(s * gv);
                }
            }
        }
    }
}

// ---------------------------------------------------------------------------
// 5. RoPE in-place on bf16 q,k, layout [B, L, H, HD]
// ---------------------------------------------------------------------------
__global__ __launch_bounds__(256) void rope_kernel(
    unsigned short* __restrict__ q, unsigned short* __restrict__ k,
    const float* __restrict__ cosb, const float* __restrict__ sinb)
{
    int gid = blockIdx.x * 256 + threadIdx.x;  // B*L*H*32
    int dp = gid & 31;
    int h  = (gid >> 5) & (NHEAD - 1);
    int l  = (gid >> 9) & (SEQ - 1);
    int b  = gid >> 19;
    size_t base = (((size_t)b * SEQ + l) * NHEAD + h) * HDIM;
    float c1 = cosb[l * HDIM + dp],      s1 = sinb[l * HDIM + dp];
    float c2 = cosb[l * HDIM + dp + 32], s2 = sinb[l * HDIM + dp + 32];
    float q1 = bf2f(q[base + dp]), q2 = bf2f(q[base + dp + 32]);
    q[base + dp]      = f2bf(q1 * c1 - q2 * s1);
    q[base + dp + 32] = f2bf(q2 * c2 + q1 * s2);
    float k1 = bf2f(k[base + dp]), k2 = bf2f(k[base + dp + 32]);
    k[base + dp]      = f2bf(k1 * c1 - k2 * s1);
    k[base + dp + 32] = f2bf(k2 * c2 + k1 * s2);
}

// ---------------------------------------------------------------------------
// 6. Causal flash attention: bf16 q/k/v/o, fp32 internal math (unchanged core)
// ---------------------------------------------------------------------------
__global__ __launch_bounds__(256) void attn_kernel(
    const unsigned short* __restrict__ q, const unsigned short* __restrict__ k,
    const unsigned short* __restrict__ v, unsigned short* __restrict__ o)
{
    int blk = blockIdx.x;              // ((b*H + h)*32 + qt)
    int qt = blk & 31;
    int h  = (blk >> 5) & (NHEAD - 1);
    int b  = blk >> 9;
    int q0 = qt * 32;

    __shared__ float Qs[32][65];
    __shared__ float Ks[64][65];
    __shared__ float Vs[64][65];
    __shared__ float Ps[32][65];

    int t = threadIdx.x;
    int r = t >> 3;
    int c0 = (t & 7) * 8;
    const float scale = 0.125f;

    {   // load Q tile (32x64 bf16 = 256 units of 8)
        int row = t >> 3, c8 = (t & 7) * 8;
        uint4 qv = *(const uint4*)&q[(((size_t)b * SEQ + q0 + row) * NHEAD + h) * HDIM + c8];
        const unsigned short* pu = (const unsigned short*)&qv;
        #pragma unroll
        for (int j = 0; j < 8; ++j) Qs[row][c8 + j] = bf2f(pu[j]);
    }
    __syncthreads();

    float acc[8] = {};
    float m = -1e30f, lsum = 0.f;

    int kend = q0 + 32;
    int nkt = (kend + 63) >> 6;
    for (int kt = 0; kt < nkt; ++kt) {
        int k0 = kt * 64;
        #pragma unroll
        for (int i = 0; i < 2; ++i) {
            int idx = t + i * 256;
            int row = idx >> 3, c8 = (idx & 7) * 8;
            size_t gaddr = (((size_t)b * SEQ + k0 + row) * NHEAD + h) * HDIM + c8;
            uint4 kv = *(const uint4*)&k[gaddr];
            uint4 vv = *(const uint4*)&v[gaddr];
            const unsigned short* pk = (const unsigned short*)&kv;
            const unsigned short* pv = (const unsigned short*)&vv;
            #pragma unroll
            for (int j = 0; j < 8; ++j) { Ks[row][c8 + j] = bf2f(pk[j]); Vs[row][c8 + j] = bf2f(pv[j]); }
        }
        __syncthreads();

        float s[8] = {};
        #pragma unroll 8
        for (int d = 0; d < 64; ++d) {
            float qd = Qs[r][d];
            #pragma unroll
            for (int jj = 0; jj < 8; ++jj) s[jj] = fmaf(qd, Ks[c0 + jj][d], s[jj]);
        }
        float tm = -1e30f;
        #pragma unroll
        for (int jj = 0; jj < 8; ++jj) {
            bool valid = (k0 + c0 + jj) <= (q0 + r);
            s[jj] = valid ? s[jj] * scale : -1e30f;
            tm = fmaxf(tm, s[jj]);
        }
        tm = fmaxf(tm, __shfl_xor(tm, 1));
        tm = fmaxf(tm, __shfl_xor(tm, 2));
        tm = fmaxf(tm, __shfl_xor(tm, 4));
        float mnew = fmaxf(m, tm);
        float sc = expf(m - mnew);
        float psum = 0.f;
        #pragma unroll
        for (int jj = 0; jj < 8; ++jj) {
            float p = (s[jj] > -1e29f) ? expf(s[jj] - mnew) : 0.f;
            Ps[r][c0 + jj] = p;
            psum += p;
        }
        psum += __shfl_xor(psum, 1);
        psum += __shfl_xor(psum, 2);
        psum += __shfl_xor(psum, 4);
        lsum = lsum * sc + psum;
        m = mnew;
        #pragma unroll
        for (int i = 0; i < 8; ++i) acc[i] *= sc;
        __syncthreads();

        for (int j = 0; j < 64; ++j) {
            float p = Ps[r][j];
            #pragma unroll
            for (int i = 0; i < 8; ++i) acc[i] = fmaf(p, Vs[j][c0 + i], acc[i]);
        }
        __syncthreads();
    }

    float inv = 1.0f / lsum;
    size_t obase = (((size_t)b * SEQ + q0 + r) * NHEAD + h) * HDIM + c0;
    ushort4 o0, o1;
    o0.x = f2bf(acc[0] * inv); o0.y = f2bf(acc[1] * inv);
    o0.z = f2bf(acc[2] * inv); o0.w = f2bf(acc[3] * inv);
    o1.x = f2bf(acc[4] * inv); o1.y = f2bf(acc[5] * inv);
    o1.z = f2bf(acc[6] * inv); o1.w = f2bf(acc[7] * inv);
    *(ushort4*)&o[obase]     = o0;
    *(ushort4*)&o[obase + 4] = o1;
}

// ---------------------------------------------------------------------------
// Launch
// ---------------------------------------------------------------------------
extern "C" void kernel_launch(void* const* d_in, const int* in_sizes, int n_in,
                              void* d_out, int out_size, void* d_ws, size_t ws_size,
                              hipStream_t stream)
{
    const float* xp   = (const float*)d_in[0];
    const int*   bnd  = (const int*)d_in[1];
    const float* xres = (const float*)d_in[3];
    const float* cosb = (const float*)d_in[4];
    const float* sinb = (const float*)d_in[5];
    const float* wq = (const float*)d_in[7];
    const float* wk = (const float*)d_in[8];
    const float* wv = (const float*)d_in[9];
    const float* wo = (const float*)d_in[10];
    const float* w1 = (const float*)d_in[11];
    const float* w2 = (const float*)d_in[12];
    const float* w3 = (const float*)d_in[13];
    const float* anw = (const float*)d_in[14];
    const float* fnw = (const float*)d_in[15];
    const float* nw  = (const float*)d_in[16];

    char* wsb = (char*)d_ws;
    float* x           = (float*)wsb;                                  // 16 MB
    unsigned short* h  = (unsigned short*)(wsb + (16u << 20));         // 8 MB
    unsigned short* qb = (unsigned short*)(wsb + (24u << 20));         // 8 MB
    unsigned short* kb = (unsigned short*)(wsb + (32u << 20));         // 8 MB
    unsigned short* vb = (unsigned short*)(wsb + (40u << 20));         // 8 MB
    unsigned short* ob = (unsigned short*)(wsb + (48u << 20));         // 8 MB
    unsigned short* g  = qb;                                           // 32 MB alias (FFN phase)
    unsigned short* wT = (unsigned short*)(wsb + (56u << 20));         // 8 MB scratch

    dim3 blk(256);
    dim3 gemmD(DIM / 128, MROWS / 128);     // (8, 32)
    dim3 gemmF(FFDIM / 128, MROWS / 128);   // (32, 32)
    dim3 ctD(DIM / 32, DIM / 32);           // W [1024][1024]
    dim3 ctF13(FFDIM / 32, DIM / 32);       // w1/w3 [1024][4096] -> WT [4096][1024]
    dim3 ctF2(DIM / 32, FFDIM / 32);        // w2 [4096][1024] -> WT [1024][4096]

    gather_kernel<<<MROWS, blk, 0, stream>>>(xp, bnd, xres, x);

    for (int l = 0; l < NLAYER; ++l) {
        const float* wql = wq + (size_t)l * DIM * DIM;
        const float* wkl = wk + (size_t)l * DIM * DIM;
        const float* wvl = wv + (size_t)l * DIM * DIM;
        const float* wol = wo + (size_t)l * DIM * DIM;
        const float* w1l = w1 + (size_t)l * DIM * FFDIM;
        const float* w2l = w2 + (size_t)l * FFDIM * DIM;
        const float* w3l = w3 + (size_t)l * DIM * FFDIM;

        // ---- attention block ----
        rmsnorm_kernel<1><<<MROWS, blk, 0, stream>>>(x, anw + (size_t)l * DIM, h);
        castT_kernel<<<ctD, blk, 0, stream>>>(wql, wT, DIM, DIM);
        gemm_bf16<0><<<gemmD, blk, 0, stream>>>((const __bf16*)h, (const __bf16*)wT, qb, DIM, DIM);
        castT_kernel<<<ctD, blk, 0, stream>>>(wkl, wT, DIM, DIM);
        gemm_bf16<0><<<gemmD, blk, 0, stream>>>((const __bf16*)h, (const __bf16*)wT, kb, DIM, DIM);
        castT_kernel<<<ctD, blk, 0, stream>>>(wvl, wT, DIM, DIM);
        gemm_bf16<0><<<gemmD, blk, 0, stream>>>((const __bf16*)h, (const __bf16*)wT, vb, DIM, DIM);
        rope_kernel<<<(BATCH * SEQ * NHEAD * 32) / 256, blk, 0, stream>>>(qb, kb, cosb, sinb);
        attn_kernel<<<BATCH * NHEAD * (SEQ / 32), blk, 0, stream>>>(qb, kb, vb, ob);
        castT_kernel<<<ctD, blk, 0, stream>>>(wol, wT, DIM, DIM);
        gemm_bf16<1><<<gemmD, blk, 0, stream>>>((const __bf16*)ob, (const __bf16*)wT, x, DIM, DIM);

        // ---- FFN block ----
        rmsnorm_kernel<1><<<MROWS, blk, 0, stream>>>(x, fnw + (size_t)l * DIM, h);
        castT_kernel<<<ctF13, blk, 0, stream>>>(w3l, wT, DIM, FFDIM);
        gemm_bf16<0><<<gemmF, blk, 0, stream>>>((const __bf16*)h, (const __bf16*)wT, g, FFDIM, DIM);
        castT_kernel<<<ctF13, blk, 0, stream>>>(w1l, wT, DIM, FFDIM);
        gemm_bf16<2><<<gemmF, blk, 0, stream>>>((const __bf16*)h, (const __bf16*)wT, g, FFDIM, DIM);
        castT_kernel<<<ctF2, blk, 0, stream>>>(w2l, wT, FFDIM, DIM);
        gemm_bf16<1><<<gemmD, blk, 0, stream>>>((const __bf16*)g, (const __bf16*)wT, x, DIM, FFDIM);
    }

    rmsnorm_kernel<0><<<MROWS, blk, 0, stream>>>(x, nw, (float*)d_out);
}

// Round 6
// 2178.360 us; speedup vs baseline: 5.0664x; 2.4608x over previous
//
#include <hip/hip_runtime.h>
#include <hip/hip_bf16.h>
#include <math.h>
#include <stddef.h>
#include <stdint.h>

#define BATCH  4
#define SEQ    1024
#define DIM    1024
#define NCHUNK 128
#define NHEAD  16
#define HDIM   64
#define NLAYER 4
#define FFDIM  4096
#define MROWS  (BATCH*SEQ)   // 4096
#define EPSV   1e-5f

#define KBLK 64
#define QBLK 128
#define WQ   32

typedef __bf16 bf16x8 __attribute__((ext_vector_type(8)));
typedef float  f32x4  __attribute__((ext_vector_type(4)));

__device__ __forceinline__ float bf2f(unsigned short u) {
    unsigned int x = ((unsigned int)u) << 16;
    return __builtin_bit_cast(float, x);
}
__device__ __forceinline__ unsigned short f2bf(float f) {
    unsigned int x = __builtin_bit_cast(unsigned int, f);
    x += 0x7fff + ((x >> 16) & 1);          // RNE
    return (unsigned short)(x >> 16);
}

// async global->LDS, 16B per lane (linear LDS dest in lane order!)
__device__ __forceinline__ void gload16(const void* g, void* l) {
    __builtin_amdgcn_global_load_lds((const __attribute__((address_space(1))) void*)g,
                                     (__attribute__((address_space(3))) void*)l, 16, 0, 0);
}

// ---------------------------------------------------------------------------
// 1. Ragged gather (fp32): x = gather(x_processed) + x_residual
// ---------------------------------------------------------------------------
__global__ __launch_bounds__(256) void gather_kernel(
    const float* __restrict__ xp, const int* __restrict__ bnd,
    const float* __restrict__ xres, float* __restrict__ x)
{
    int blk = blockIdx.x;
    int b = blk >> 10, l = blk & (SEQ - 1);
    __shared__ int sidx;
    if (threadIdx.x == 0) {
        const int* bb = bnd + b * NCHUNK;
        int lo = 0, hi = NCHUNK;
        while (lo < hi) { int mid = (lo + hi) >> 1; if (bb[mid] <= l) lo = mid + 1; else hi = mid; }
        int idx = lo - 1;
        sidx = idx < 0 ? 0 : (idx > NCHUNK - 1 ? NCHUNK - 1 : idx);
    }
    __syncthreads();
    int idx = sidx;
    int t = threadIdx.x;
    float4 a = *(const float4*)&xp[((size_t)b * NCHUNK + idx) * DIM + t * 4];
    float4 r = *(const float4*)&xres[(size_t)blk * DIM + t * 4];
    float4 o; o.x = a.x + r.x; o.y = a.y + r.y; o.z = a.z + r.z; o.w = a.w + r.w;
    *(float4*)&x[(size_t)blk * DIM + t * 4] = o;
}

// ---------------------------------------------------------------------------
// 2. RMSNorm (fp32 in). OUTBF=1 -> bf16 out, else fp32 out.
// ---------------------------------------------------------------------------
template<int OUTBF>
__global__ __launch_bounds__(256) void rmsnorm_kernel(
    const float* __restrict__ x, const float* __restrict__ w, void* __restrict__ out)
{
    int row = blockIdx.x;
    int t = threadIdx.x;
    const float4 xv = *(const float4*)&x[(size_t)row * DIM + t * 4];
    float ss = xv.x * xv.x + xv.y * xv.y + xv.z * xv.z + xv.w * xv.w;
    #pragma unroll
    for (int m = 1; m < 64; m <<= 1) ss += __shfl_xor(ss, m);
    __shared__ float ws_[4];
    if ((t & 63) == 0) ws_[t >> 6] = ss;
    __syncthreads();
    float tot = ws_[0] + ws_[1] + ws_[2] + ws_[3];
    float rs = rsqrtf(tot * (1.0f / DIM) + EPSV);
    const float4 wv = *(const float4*)&w[t * 4];
    float4 o;
    o.x = xv.x * rs * wv.x; o.y = xv.y * rs * wv.y;
    o.z = xv.z * rs * wv.z; o.w = xv.w * rs * wv.w;
    if (OUTBF) {
        ushort4 p;
        p.x = f2bf(o.x); p.y = f2bf(o.y); p.z = f2bf(o.z); p.w = f2bf(o.w);
        *(ushort4*)&((unsigned short*)out)[(size_t)row * DIM + t * 4] = p;
    } else {
        *(float4*)&((float*)out)[(size_t)row * DIM + t * 4] = o;
    }
}

// ---------------------------------------------------------------------------
// 3. Weight cast+transpose: W fp32 [Kd][N] -> WT bf16 [N][Kd]
// ---------------------------------------------------------------------------
__global__ __launch_bounds__(256) void castT_kernel(
    const float* __restrict__ W, unsigned short* __restrict__ WT, int Kd, int N)
{
    int n0 = blockIdx.x * 32, k0 = blockIdx.y * 32;
    __shared__ float tile[32][33];
    int t = threadIdx.x;
    int r = t >> 3, c4 = (t & 7) * 4;
    float4 v = *(const float4*)&W[(size_t)(k0 + r) * N + n0 + c4];
    tile[r][c4 + 0] = v.x; tile[r][c4 + 1] = v.y;
    tile[r][c4 + 2] = v.z; tile[r][c4 + 3] = v.w;
    __syncthreads();
    ushort4 p;
    p.x = f2bf(tile[c4 + 0][r]); p.y = f2bf(tile[c4 + 1][r]);
    p.z = f2bf(tile[c4 + 2][r]); p.w = f2bf(tile[c4 + 3][r]);
    *(ushort4*)&WT[(size_t)(n0 + r) * Kd + k0 + c4] = p;
}

// ---------------------------------------------------------------------------
// 4. bf16 MFMA GEMM (m97 structure): C[M,N] = A[M,Kd] @ WT[N,Kd]^T
//    MODE 0: C(bf16) = AB    MODE 1: C(fp32) += AB    MODE 2: C(bf16) = silu(AB)*C
// ---------------------------------------------------------------------------
template<int MODE>
__global__ __launch_bounds__(256) void gemm_bf16(
    const __bf16* __restrict__ A, const __bf16* __restrict__ WT,
    void* __restrict__ C, int N, int Kd)
{
    __shared__ __bf16 As[128 * 32];
    __shared__ __bf16 Bs[128 * 32];
    int t = threadIdx.x;
    int l = t & 63, w = t >> 6;
    int wr = w >> 1, wc = w & 1;
    int bm = blockIdx.y * 128, bn = blockIdx.x * 128;
    int l15 = l & 15, l4 = l >> 4;
    int kOff = l4 * 8;

    f32x4 acc[4][4];
    #pragma unroll
    for (int m = 0; m < 4; ++m)
        #pragma unroll
        for (int n = 0; n < 4; ++n)
            acc[m][n] = (f32x4){0.f, 0.f, 0.f, 0.f};

    for (int k0 = 0; k0 < Kd; k0 += 32) {
        #pragma unroll
        for (int i = 0; i < 2; ++i) {
            int idx = t + i * 256;
            gload16(A + (size_t)(bm + (idx >> 2)) * Kd + k0 + (idx & 3) * 8, &As[idx * 8]);
        }
        #pragma unroll
        for (int i = 0; i < 2; ++i) {
            int idx = t + i * 256;
            gload16(WT + (size_t)(bn + (idx >> 2)) * Kd + k0 + (idx & 3) * 8, &Bs[idx * 8]);
        }
        __syncthreads();
        bf16x8 af[4], bf[4];
        #pragma unroll
        for (int m = 0; m < 4; ++m)
            af[m] = *(const bf16x8*)&As[(wr * 64 + m * 16 + l15) * 32 + kOff];
        #pragma unroll
        for (int n = 0; n < 4; ++n)
            bf[n] = *(const bf16x8*)&Bs[(wc * 64 + n * 16 + l15) * 32 + kOff];
        #pragma unroll
        for (int m = 0; m < 4; ++m)
            #pragma unroll
            for (int n = 0; n < 4; ++n)
                acc[m][n] = __builtin_amdgcn_mfma_f32_16x16x32_bf16(af[m], bf[n], acc[m][n], 0, 0, 0);
        __syncthreads();
    }

    int rBase = bm + wr * 64 + l4 * 4;
    int cBase = bn + wc * 64 + l15;
    #pragma unroll
    for (int m = 0; m < 4; ++m) {
        #pragma unroll
        for (int n = 0; n < 4; ++n) {
            int col = cBase + n * 16;
            #pragma unroll
            for (int r = 0; r < 4; ++r) {
                int row = rBase + m * 16 + r;
                float val = acc[m][n][r];
                if (MODE == 0) {
                    ((unsigned short*)C)[(size_t)row * N + col] = f2bf(val);
                } else if (MODE == 1) {
                    ((float*)C)[(size_t)row * N + col] += val;
                } else {
                    unsigned short* p = &((unsigned short*)C)[(size_t)row * N + col];
                    float gv = bf2f(*p);
                    float s = val / (1.f + expf(-val));
                    *p = f2bf(s * gv);
                }
            }
        }
    }
}

// ---------------------------------------------------------------------------
// 5. RoPE in-place on bf16 q,k, layout [B, L, H*HD]
// ---------------------------------------------------------------------------
__global__ __launch_bounds__(256) void rope_kernel(
    unsigned short* __restrict__ q, unsigned short* __restrict__ k,
    const float* __restrict__ cosb, const float* __restrict__ sinb)
{
    int gid = blockIdx.x * 256 + threadIdx.x;  // B*L*H*32
    int dp = gid & 31;
    int h  = (gid >> 5) & (NHEAD - 1);
    int l  = (gid >> 9) & (SEQ - 1);
    int b  = gid >> 19;
    size_t base = (((size_t)b * SEQ + l) * NHEAD + h) * HDIM;
    float c1 = cosb[l * HDIM + dp],      s1 = sinb[l * HDIM + dp];
    float c2 = cosb[l * HDIM + dp + 32], s2 = sinb[l * HDIM + dp + 32];
    float q1 = bf2f(q[base + dp]), q2 = bf2f(q[base + dp + 32]);
    q[base + dp]      = f2bf(q1 * c1 - q2 * s1);
    q[base + dp + 32] = f2bf(q2 * c2 + q1 * s2);
    float k1 = bf2f(k[base + dp]), k2 = bf2f(k[base + dp + 32]);
    k[base + dp]      = f2bf(k1 * c1 - k2 * s1);
    k[base + dp + 32] = f2bf(k2 * c2 + k1 * s2);
}

// ---------------------------------------------------------------------------
// 6. MFMA causal flash attention.
//    Block = 4 waves, QBLK=128 q rows of one (b,h); wave owns WQ=32 rows.
//    K-tile = 64. LDS: Ks [kv][hd] swizzled, Vt [hd][kv] swizzled,
//    Ps per-wave [q][kv] swizzled. XOR swizzle: byte ^= (row&7)<<4.
// ---------------------------------------------------------------------------
__global__ __launch_bounds__(256) void attn_mfma(
    const unsigned short* __restrict__ q, const unsigned short* __restrict__ k,
    const unsigned short* __restrict__ v, unsigned short* __restrict__ o)
{
    __shared__ __align__(16) unsigned short Ks[KBLK * 64];     // 8 KB
    __shared__ __align__(16) unsigned short Vt[64 * KBLK];     // 8 KB
    __shared__ __align__(16) unsigned short Ps[4][WQ * KBLK];  // 16 KB

    int blk = blockIdx.x;                 // ((b*H + h)*8 + qb)
    int qb = blk & 7;
    int h  = (blk >> 3) & (NHEAD - 1);
    int b  = blk >> 7;
    int q0 = qb * QBLK;

    int t = threadIdx.x;
    int l = t & 63, w = t >> 6;
    int l15 = l & 15, l4 = l >> 4;
    int qw0 = q0 + w * WQ;
    const float scale = 0.125f;

    // Q fragments [rowset][kstep], held in registers for the whole kernel
    bf16x8 qf[2][2];
    #pragma unroll
    for (int s = 0; s < 2; ++s)
        #pragma unroll
        for (int ks = 0; ks < 2; ++ks)
            qf[s][ks] = *(const bf16x8*)&q[(size_t)(b * SEQ + qw0 + s * 16 + l15) * DIM
                                           + h * HDIM + ks * 32 + l4 * 8];

    f32x4 oacc[2][4];
    float mrun[2][4], lrun[2][4];
    #pragma unroll
    for (int s = 0; s < 2; ++s) {
        #pragma unroll
        for (int cb = 0; cb < 4; ++cb) oacc[s][cb] = (f32x4){0.f, 0.f, 0.f, 0.f};
        #pragma unroll
        for (int rr = 0; rr < 4; ++rr) { mrun[s][rr] = -3.0e38f; lrun[s][rr] = 0.f; }
    }

    // staging assignments
    int krow = t >> 3;          // 0..31  (+i*32)
    int kc8  = (t & 7) * 8;     // hd base for K load
    int vrow = t & 31;          // kv     (+i*32)
    int vh8  = (t >> 5) * 8;    // hd base for V load

    int nkt = 2 * (qb + 1);
    uint4 kr[2], vr[2];
    {
        #pragma unroll
        for (int i = 0; i < 2; ++i) {
            kr[i] = *(const uint4*)&k[(size_t)(b * SEQ + 0 + krow + i * 32) * DIM + h * HDIM + kc8];
            vr[i] = *(const uint4*)&v[(size_t)(b * SEQ + 0 + vrow + i * 32) * DIM + h * HDIM + vh8];
        }
    }

    for (int kt = 0; kt < nkt; ++kt) {
        int k0 = kt * KBLK;
        __syncthreads();   // previous compute done; LDS free
        // write staged tile to LDS (swizzled)
        #pragma unroll
        for (int i = 0; i < 2; ++i) {
            int kv = krow + i * 32;
            int kbyte = (kv * 128 + kc8 * 2) ^ ((kv & 7) << 4);
            *(uint4*)((char*)Ks + kbyte) = kr[i];
            int kvv = vrow + i * 32;
            const unsigned short* pv = (const unsigned short*)&vr[i];
            #pragma unroll
            for (int j = 0; j < 8; ++j) {
                int hd = vh8 + j;
                int vbyte = (hd * 128 + kvv * 2) ^ ((hd & 7) << 4);
                *(unsigned short*)((char*)Vt + vbyte) = pv[j];
            }
        }
        __syncthreads();
        // prefetch next tile into registers (hides HBM/L2 latency under compute)
        if (kt + 1 < nkt) {
            int kn = (kt + 1) * KBLK;
            #pragma unroll
            for (int i = 0; i < 2; ++i) {
                kr[i] = *(const uint4*)&k[(size_t)(b * SEQ + kn + krow + i * 32) * DIM + h * HDIM + kc8];
                vr[i] = *(const uint4*)&v[(size_t)(b * SEQ + kn + vrow + i * 32) * DIM + h * HDIM + vh8];
            }
        }

        if (k0 <= qw0 + WQ - 1) {   // wave has at least one unmasked element
            // ---- QK^T: S[32 q][64 kv] ----
            f32x4 sacc[2][4];
            #pragma unroll
            for (int s = 0; s < 2; ++s)
                #pragma unroll
                for (int cb = 0; cb < 4; ++cb) sacc[s][cb] = (f32x4){0.f, 0.f, 0.f, 0.f};
            #pragma unroll
            for (int cb = 0; cb < 4; ++cb) {
                #pragma unroll
                for (int ks = 0; ks < 2; ++ks) {
                    int byte = ((cb * 16 + l15) * 128 + ks * 64 + l4 * 16) ^ ((l15 & 7) << 4);
                    bf16x8 kf = *(const bf16x8*)((const char*)Ks + byte);
                    sacc[0][cb] = __builtin_amdgcn_mfma_f32_16x16x32_bf16(qf[0][ks], kf, sacc[0][cb], 0, 0, 0);
                    sacc[1][cb] = __builtin_amdgcn_mfma_f32_16x16x32_bf16(qf[1][ks], kf, sacc[1][cb], 0, 0, 0);
                }
            }
            // ---- online softmax (C-layout: col=l15+cb*16, row=l4*4+rr) ----
            #pragma unroll
            for (int s = 0; s < 2; ++s) {
                bool domask = (k0 + KBLK - 1) > (qw0 + s * 16);
                #pragma unroll
                for (int cb = 0; cb < 4; ++cb)
                    #pragma unroll
                    for (int rr = 0; rr < 4; ++rr) {
                        float sv = sacc[s][cb][rr] * scale;
                        if (domask) {
                            int kvi = k0 + cb * 16 + l15;
                            int qi  = qw0 + s * 16 + l4 * 4 + rr;
                            sv = (kvi <= qi) ? sv : -3.0e38f;
                        }
                        sacc[s][cb][rr] = sv;
                    }
                #pragma unroll
                for (int rr = 0; rr < 4; ++rr) {
                    float tm = fmaxf(fmaxf(sacc[s][0][rr], sacc[s][1][rr]),
                                     fmaxf(sacc[s][2][rr], sacc[s][3][rr]));
                    tm = fmaxf(tm, __shfl_xor(tm, 1));
                    tm = fmaxf(tm, __shfl_xor(tm, 2));
                    tm = fmaxf(tm, __shfl_xor(tm, 4));
                    tm = fmaxf(tm, __shfl_xor(tm, 8));
                    float mnew = fmaxf(mrun[s][rr], tm);
                    float scf = __expf(mrun[s][rr] - mnew);
                    float psum = 0.f;
                    #pragma unroll
                    for (int cb = 0; cb < 4; ++cb) {
                        float sv = sacc[s][cb][rr];
                        float p = (sv > -1.0e37f) ? __expf(sv - mnew) : 0.f;
                        sacc[s][cb][rr] = p;
                        psum += p;
                    }
                    psum += __shfl_xor(psum, 1);
                    psum += __shfl_xor(psum, 2);
                    psum += __shfl_xor(psum, 4);
                    psum += __shfl_xor(psum, 8);
                    lrun[s][rr] = lrun[s][rr] * scf + psum;
                    mrun[s][rr] = mnew;
                    #pragma unroll
                    for (int cb = 0; cb < 4; ++cb) oacc[s][cb][rr] *= scf;
                }
                // write P (bf16) to per-wave LDS in [q][kv] layout, swizzled
                #pragma unroll
                for (int cb = 0; cb < 4; ++cb)
                    #pragma unroll
                    for (int rr = 0; rr < 4; ++rr) {
                        int qrow = s * 16 + l4 * 4 + rr;
                        int byte = (qrow * 128 + (cb * 16 + l15) * 2) ^ ((qrow & 7) << 4);
                        *(unsigned short*)((char*)Ps[w] + byte) = f2bf(sacc[s][cb][rr]);
                    }
            }
            // ---- PV: O += P @ V ----
            bf16x8 pa[2][2];
            #pragma unroll
            for (int s = 0; s < 2; ++s)
                #pragma unroll
                for (int ks = 0; ks < 2; ++ks) {
                    int byte = ((s * 16 + l15) * 128 + ks * 64 + l4 * 16) ^ ((l15 & 7) << 4);
                    pa[s][ks] = *(const bf16x8*)((const char*)Ps[w] + byte);
                }
            #pragma unroll
            for (int cb = 0; cb < 4; ++cb) {
                #pragma unroll
                for (int ks = 0; ks < 2; ++ks) {
                    int byte = ((cb * 16 + l15) * 128 + ks * 64 + l4 * 16) ^ ((l15 & 7) << 4);
                    bf16x8 vf = *(const bf16x8*)((const char*)Vt + byte);
                    oacc[0][cb] = __builtin_amdgcn_mfma_f32_16x16x32_bf16(pa[0][ks], vf, oacc[0][cb], 0, 0, 0);
                    oacc[1][cb] = __builtin_amdgcn_mfma_f32_16x16x32_bf16(pa[1][ks], vf, oacc[1][cb], 0, 0, 0);
                }
            }
        }
    }

    // epilogue: O /= lsum, store bf16
    #pragma unroll
    for (int s = 0; s < 2; ++s)
        #pragma unroll
        for (int rr = 0; rr < 4; ++rr) {
            float inv = 1.0f / lrun[s][rr];
            int qrow = qw0 + s * 16 + l4 * 4 + rr;
            #pragma unroll
            for (int cb = 0; cb < 4; ++cb)
                o[(size_t)(b * SEQ + qrow) * DIM + h * HDIM + cb * 16 + l15] =
                    f2bf(oacc[s][cb][rr] * inv);
        }
}

// ---------------------------------------------------------------------------
// Launch
// ---------------------------------------------------------------------------
extern "C" void kernel_launch(void* const* d_in, const int* in_sizes, int n_in,
                              void* d_out, int out_size, void* d_ws, size_t ws_size,
                              hipStream_t stream)
{
    const float* xp   = (const float*)d_in[0];
    const int*   bnd  = (const int*)d_in[1];
    const float* xres = (const float*)d_in[3];
    const float* cosb = (const float*)d_in[4];
    const float* sinb = (const float*)d_in[5];
    const float* wq = (const float*)d_in[7];
    const float* wk = (const float*)d_in[8];
    const float* wv = (const float*)d_in[9];
    const float* wo = (const float*)d_in[10];
    const float* w1 = (const float*)d_in[11];
    const float* w2 = (const float*)d_in[12];
    const float* w3 = (const float*)d_in[13];
    const float* anw = (const float*)d_in[14];
    const float* fnw = (const float*)d_in[15];
    const float* nw  = (const float*)d_in[16];

    char* wsb = (char*)d_ws;
    float* x           = (float*)wsb;                                  // 16 MB
    unsigned short* h  = (unsigned short*)(wsb + (16u << 20));         // 8 MB
    unsigned short* qb = (unsigned short*)(wsb + (24u << 20));         // 8 MB
    unsigned short* kb = (unsigned short*)(wsb + (32u << 20));         // 8 MB
    unsigned short* vb = (unsigned short*)(wsb + (40u << 20));         // 8 MB
    unsigned short* ob = (unsigned short*)(wsb + (48u << 20));         // 8 MB
    unsigned short* g  = qb;                                           // 32 MB alias (FFN phase)
    unsigned short* wT = (unsigned short*)(wsb + (56u << 20));         // 8 MB scratch

    dim3 blk(256);
    dim3 gemmD(DIM / 128, MROWS / 128);     // (8, 32)
    dim3 gemmF(FFDIM / 128, MROWS / 128);   // (32, 32)
    dim3 ctD(DIM / 32, DIM / 32);
    dim3 ctF13(FFDIM / 32, DIM / 32);
    dim3 ctF2(DIM / 32, FFDIM / 32);

    gather_kernel<<<MROWS, blk, 0, stream>>>(xp, bnd, xres, x);

    for (int l = 0; l < NLAYER; ++l) {
        const float* wql = wq + (size_t)l * DIM * DIM;
        const float* wkl = wk + (size_t)l * DIM * DIM;
        const float* wvl = wv + (size_t)l * DIM * DIM;
        const float* wol = wo + (size_t)l * DIM * DIM;
        const float* w1l = w1 + (size_t)l * DIM * FFDIM;
        const float* w2l = w2 + (size_t)l * FFDIM * DIM;
        const float* w3l = w3 + (size_t)l * DIM * FFDIM;

        // ---- attention block ----
        rmsnorm_kernel<1><<<MROWS, blk, 0, stream>>>(x, anw + (size_t)l * DIM, h);
        castT_kernel<<<ctD, blk, 0, stream>>>(wql, wT, DIM, DIM);
        gemm_bf16<0><<<gemmD, blk, 0, stream>>>((const __bf16*)h, (const __bf16*)wT, qb, DIM, DIM);
        castT_kernel<<<ctD, blk, 0, stream>>>(wkl, wT, DIM, DIM);
        gemm_bf16<0><<<gemmD, blk, 0, stream>>>((const __bf16*)h, (const __bf16*)wT, kb, DIM, DIM);
        castT_kernel<<<ctD, blk, 0, stream>>>(wvl, wT, DIM, DIM);
        gemm_bf16<0><<<gemmD, blk, 0, stream>>>((const __bf16*)h, (const __bf16*)wT, vb, DIM, DIM);
        rope_kernel<<<(BATCH * SEQ * NHEAD * 32) / 256, blk, 0, stream>>>(qb, kb, cosb, sinb);
        attn_mfma<<<BATCH * NHEAD * (SEQ / QBLK), blk, 0, stream>>>(qb, kb, vb, ob);
        castT_kernel<<<ctD, blk, 0, stream>>>(wol, wT, DIM, DIM);
        gemm_bf16<1><<<gemmD, blk, 0, stream>>>((const __bf16*)ob, (const __bf16*)wT, x, DIM, DIM);

        // ---- FFN block ----
        rmsnorm_kernel<1><<<MROWS, blk, 0, stream>>>(x, fnw + (size_t)l * DIM, h);
        castT_kernel<<<ctF13, blk, 0, stream>>>(w3l, wT, DIM, FFDIM);
        gemm_bf16<0><<<gemmF, blk, 0, stream>>>((const __bf16*)h, (const __bf16*)wT, g, FFDIM, DIM);
        castT_kernel<<<ctF13, blk, 0, stream>>>(w1l, wT, DIM, FFDIM);
        gemm_bf16<2><<<gemmF, blk, 0, stream>>>((const __bf16*)h, (const __bf16*)wT, g, FFDIM, DIM);
        castT_kernel<<<ctF2, blk, 0, stream>>>(w2l, wT, FFDIM, DIM);
        gemm_bf16<1><<<gemmD, blk, 0, stream>>>((const __bf16*)g, (const __bf16*)wT, x, DIM, FFDIM);
    }

    rmsnorm_kernel<0><<<MROWS, blk, 0, stream>>>(x, nw, (float*)d_out);
}